// Round 19
// baseline (1514.746 us; speedup 1.0000x reference)
//
#include <hip/hip_runtime.h>
#include <stdint.h>

#define B_ 32
#define T_ 2000
#define E_ 256
#define S_ 64
#define L_ 3
#define BT_ (B_*T_)
#define NC_ 16
#define CL_ 125
#define TS_ 25
#define NT_ (CL_/TS_)
#define TP_ (T_+16)

typedef short s8v __attribute__((ext_vector_type(8)));
typedef short s4v __attribute__((ext_vector_type(4)));
typedef float f4v __attribute__((ext_vector_type(4)));
typedef float f2v __attribute__((ext_vector_type(2)));
typedef unsigned short us;

__device__ __forceinline__ float b2f(us u){
    return __uint_as_float(((unsigned int)u) << 16);
}
__device__ __forceinline__ us f2b(float f){
    unsigned int x = __float_as_uint(f);
    x += 0x7fffu + ((x >> 16) & 1u);   // RNE
    return (us)(x >> 16);
}

// ---------------- f32 -> bf16 weight pack (4 elems/thread, exact grids) ----
__global__ __launch_bounds__(256) void cvtw_k(const float* __restrict__ src,
    us* __restrict__ dst)
{
    int idx = blockIdx.x*256 + threadIdx.x;
    f4v v = *(const f4v*)(src + (size_t)idx*4);
    s4v o;
    #pragma unroll
    for (int j=0;j<4;j++) o[j] = (short)f2b(v[j]);
    *(s4v*)(dst + (size_t)idx*4) = o;
}

// ---------------- pack B_w|C_w -> WBC[l][128][256] bf16 --------------------
__global__ __launch_bounds__(256) void packbc_k(const float* __restrict__ Bw,
    const float* __restrict__ Cw, us* __restrict__ wbc)
{
    int idx = blockIdx.x*256 + threadIdx.x;   // L_*128*256
    int i = idx & 255; int r = (idx >> 8) & 127; int l = idx >> 15;
    const float* src = (r < 64) ? (Bw + ((size_t)l*S_ + r)*E_ + i)
                                : (Cw + ((size_t)l*S_ + (r-64))*E_ + i);
    wbc[idx] = f2b(*src);
}

// ---------------- pack ctx_w (j,c,i,tap) f32 -> wp[j][c][tap*256+i] bf16 ---
__global__ __launch_bounds__(256) void packw_k(const float* __restrict__ cw,
    us* __restrict__ wp)
{
    int idx = blockIdx.x*256 + threadIdx.x;   // 4*64*768
    int i2 = idx % 768; int r = idx / 768;
    int c = r & 63; int j = r >> 6;
    int tap = i2 >> 8; int i = i2 & 255;
    wp[idx] = f2b(cw[(((size_t)(j*64 + c))*E_ + i)*3 + tap]);
}

// ---------------- embedding: x0 = bf16(tok_emb[tok] + pos_emb[t]) ----------
__global__ __launch_bounds__(256) void embed_k(const int* __restrict__ tok,
    const float* __restrict__ te, const float* __restrict__ pe, us* __restrict__ x0)
{
    int idx = blockIdx.x*256 + threadIdx.x;      // BT_*32
    int dg = idx & 31; int bt = idx >> 5; int t = bt % T_;
    int tk = tok[bt] & 255;                      // V=256
    const float* ta = te + (size_t)tk*E_ + dg*8;
    const float* pa = pe + (size_t)t*E_ + dg*8;
    f4v a0 = *(const f4v*)ta, a1 = *(const f4v*)(ta+4);
    f4v p0 = *(const f4v*)pa, p1 = *(const f4v*)(pa+4);
    s8v o;
    #pragma unroll
    for (int j=0;j<4;j++){
        o[j]   = (short)f2b(a0[j] + p0[j]);
        o[j+4] = (short)f2b(a1[j] + p1[j]);
    }
    *(s8v*)(x0 + (size_t)bt*E_ + dg*8) = o;
}

// ---------------- per-layer constants: dt, dA^T, (dA^CL)^T -----------------
__global__ __launch_bounds__(256) void lconst_k(const float* __restrict__ dt_w,
    const float* __restrict__ A_log, float* __restrict__ dtv,
    float* __restrict__ dAT, float* __restrict__ dApT)
{
    int idx = blockIdx.x*256 + threadIdx.x;      // E_*S_
    int d = idx & (E_-1); int s = idx >> 8;
    float dt = log1pf(expf(dt_w[d]));            // softplus
    float A  = -expf(A_log[d*S_ + s]);
    float dA = 1.f + dt*A;
    dAT[s*E_ + d]  = dA;
    dApT[s*E_ + d] = powf(dA, (float)CL_);
    if (s == 0) dtv[d] = dt;
}

// ---------------- depthwise causal conv(4) + bias + SiLU -------------------
__global__ __launch_bounds__(256) void dwconv_k(const us* __restrict__ xin,
    const float* __restrict__ cw, const float* __restrict__ cb, us* __restrict__ xc)
{
    int idx = blockIdx.x*256 + threadIdx.x;      // BT_*32
    int dg = idx & 31; int bt = idx >> 5; int t = bt % T_;
    int d0 = dg*8;
    float acc[8]; float w[8][4];
    #pragma unroll
    for (int j=0;j<8;j++){
        f4v wv = *(const f4v*)(cw + (size_t)(d0+j)*4);
        #pragma unroll
        for (int k=0;k<4;k++) w[j][k] = wv[k];
        acc[j] = cb[d0+j];
    }
    #pragma unroll
    for (int k=0;k<4;k++){
        if (t + k - 3 >= 0){
            s8v xv = *(const s8v*)(xin + (size_t)(bt + k - 3)*E_ + d0);
            #pragma unroll
            for (int j=0;j<8;j++) acc[j] = fmaf(b2f((us)xv[j]), w[j][k], acc[j]);
        }
    }
    s8v o;
    #pragma unroll
    for (int j=0;j<8;j++){ float v = acc[j]; v = v / (1.f + expf(-v)); o[j] = (short)f2b(v); }
    *(s8v*)(xc + (size_t)bt*E_ + d0) = o;
}

// ---------------- MFMA GEMM: C[m,n] = sum_k A[m,k]*W[n,k] ------------------
// BNT = 64 or 128 (block tile is BM x BNT, 4 waves as 2x2 over 64 x BNT/2)
// AMODE 0: A1+m*lda+k | 2: concat(A1,A2) | 4: ctx taps, shift=1<<blockIdx.y
// EPI 0: bf16 | 1: split cols 256/256 -> C1,C2 bf16 | 2: f32 plain
//     5: +bias bf16 | 6: +bias relu f32
#define BM 128
#define BK 32

template<int AMODE, int EPI, int BNT>
__global__ __launch_bounds__(256)
void gemm_k(const us* __restrict__ A1, const us* __restrict__ A2,
            int lda, int shift,
            const us* __restrict__ W, int ldw,
            void* __restrict__ C1, void* __restrict__ C2,
            const float* __restrict__ bias,
            int ldc, int K)
{
    constexpr int NR = BNT/32;                 // 2 (BNT=64) or 4 (BNT=128)
    __shared__ us Al[BM*BK];                   // seg-linear: elem=(row*4+ks)*8
    __shared__ us Bl[BNT*BK];
    const int tid = threadIdx.x;
    const int wid = tid >> 6, lane = tid & 63;
    const int m0 = blockIdx.x * BM;
    const int n0 = blockIdx.y * BNT;
    const int wr = wid >> 1, wc = wid & 1;
    int sh = shift;
    if constexpr (AMODE==4) sh = 1 << blockIdx.y;
    f4v acc[4][NR];
    #pragma unroll
    for (int a=0;a<4;a++)
        #pragma unroll
        for (int b=0;b<NR;b++) acc[a][b] = (f4v){0.f,0.f,0.f,0.f};

    for (int k0 = 0; k0 < K; k0 += BK){
        if (k0) __syncthreads();               // prev tile's readers done
        #pragma unroll
        for (int i=0;i<2;i++){
            int g = i*256 + tid;               // 0..511
            int row = g >> 2, ks = g & 3;
            const us* src;
            if constexpr (AMODE==0){
                src = A1 + (size_t)(m0+row)*lda + k0 + ks*8;
            } else if constexpr (AMODE==2){
                int kk = k0 + ks*8;
                const us* base = (kk < E_) ? A1 : A2;
                src = base + (size_t)(m0+row)*E_ + (kk & (E_-1));
            } else {
                int kk = k0 + ks*8;
                int tap = kk >> 8; int kin = kk & (E_-1);
                int m = m0 + row; int bb = m / T_; int tt = m - bb*T_;
                src = A1 + ((size_t)bb*TP_ + 8 + tt + (tap-1)*sh)*E_ + kin;
            }
            __builtin_amdgcn_global_load_lds(
                (const __attribute__((address_space(1))) void*)src,
                (__attribute__((address_space(3))) void*)(Al + (size_t)g*8), 16, 0, 0);
        }
        #pragma unroll
        for (int i=0;i<BNT/64;i++){
            int g = i*256 + tid;
            int row = g >> 2, ks = g & 3;
            const us* src = W + (size_t)(n0+row)*ldw + k0 + ks*8;
            __builtin_amdgcn_global_load_lds(
                (const __attribute__((address_space(1))) void*)src,
                (__attribute__((address_space(3))) void*)(Bl + (size_t)g*8), 16, 0, 0);
        }
        __syncthreads();                       // vmcnt(0) drained before barrier

        s8v af[4], bfr[NR];
        #pragma unroll
        for (int mr=0;mr<4;mr++)
            af[mr] = *(const s8v*)(Al + ((size_t)(wr*64 + mr*16 + (lane&15))*4 + (lane>>4))*8);
        #pragma unroll
        for (int nr=0;nr<NR;nr++)
            bfr[nr] = *(const s8v*)(Bl + ((size_t)(wc*(BNT/2) + nr*16 + (lane&15))*4 + (lane>>4))*8);
        #pragma unroll
        for (int mr=0;mr<4;mr++)
            #pragma unroll
            for (int nr=0;nr<NR;nr++)
                acc[mr][nr] = __builtin_amdgcn_mfma_f32_16x16x32_bf16(af[mr], bfr[nr], acc[mr][nr], 0, 0, 0);
    }
    #pragma unroll
    for (int mr=0;mr<4;mr++){
        #pragma unroll
        for (int nr=0;nr<NR;nr++){
            int col = n0 + wc*(BNT/2) + nr*16 + (lane & 15);
            int rb  = m0 + wr*64 + mr*16 + ((lane >> 4) << 2);
            #pragma unroll
            for (int i=0;i<4;i++){
                float val = acc[mr][nr][i];
                size_t row = (size_t)(rb + i);
                if constexpr (EPI==0){
                    ((us*)C1)[row*ldc + col] = f2b(val);
                } else if constexpr (EPI==1){
                    if (col < E_) ((us*)C1)[row*E_ + col] = f2b(val);
                    else          ((us*)C2)[row*E_ + (col - E_)] = f2b(val);
                } else if constexpr (EPI==2){
                    ((float*)C1)[row*ldc + col] = val;
                } else if constexpr (EPI==5){
                    val += bias[col];
                    ((us*)C1)[row*ldc + col] = f2b(val);
                } else {                      // EPI==6: f32 out, bias+relu
                    val += bias[col];
                    val = fmaxf(val, 0.f);
                    ((float*)C1)[row*ldc + col] = val;
                }
            }
        }
    }
}

// ---------------- scan pass 1: local recurrence, ys + final-h --------------
// 1024 thr (tid = d*4+sg, 16 states each); CL=125, TS=25; tiles staged via
// global_load_lds (BC/xc tiles contiguous; 800 issuing threads).
__global__ __launch_bounds__(1024) void scan_ly(
    const float* __restrict__ dAT, const float* __restrict__ dtv,
    const us* __restrict__ xc, const float* __restrict__ BC,
    us* __restrict__ ys, us* __restrict__ H)
{
    __shared__ float sBC[TS_*128];     // 12.8 KB
    __shared__ us    sXC[TS_*256];     // 12.8 KB
    int b = blockIdx.x / NC_, c = blockIdx.x % NC_;
    int tid = threadIdx.x;
    int d = tid >> 2, sg = tid & 3, s0 = sg*16;
    f4v h4[4], dA4[4];
    #pragma unroll
    for (int q=0;q<4;q++){
        #pragma unroll
        for (int j=0;j<4;j++){ h4[q][j] = 0.f; dA4[q][j] = dAT[(s0+q*4+j)*E_ + d]; }
    }
    float dtd = dtv[d];
    int t0 = c*CL_;
    size_t base0 = (size_t)b*T_ + t0;
    if (tid < 800){
        __builtin_amdgcn_global_load_lds(
            (const __attribute__((address_space(1))) void*)(BC + base0*128 + tid*4),
            (__attribute__((address_space(3))) void*)(sBC + tid*4), 16, 0, 0);
        __builtin_amdgcn_global_load_lds(
            (const __attribute__((address_space(1))) void*)(xc + base0*E_ + tid*8),
            (__attribute__((address_space(3))) void*)(sXC + tid*8), 16, 0, 0);
    }
    __syncthreads();
    for (int tile = 0; tile < NT_; ++tile){
        for (int st = 0; st < TS_; ++st){
            int t = t0 + tile*TS_ + st;
            float u = dtd * b2f(sXC[st*256 + d]);
            const f4v* Bp = (const f4v*)(&sBC[st*128 + s0]);
            const f4v* Cp = (const f4v*)(&sBC[st*128 + 64 + s0]);
            f4v y4 = (f4v){0.f,0.f,0.f,0.f};
            #pragma unroll
            for (int q=0;q<4;q++){
                h4[q] = dA4[q]*h4[q] + Bp[q]*u;
                y4    = y4 + Cp[q]*h4[q];
            }
            float y = (y4[0]+y4[1]) + (y4[2]+y4[3]);
            y += __shfl_xor(y, 1, 4);
            y += __shfl_xor(y, 2, 4);
            if (sg == 0) ys[((size_t)b*T_ + t)*E_ + d] = f2b(y);
        }
        __syncthreads();
        if (tile+1 < NT_){
            size_t basen = base0 + (size_t)(tile+1)*TS_;
            if (tid < 800){
                __builtin_amdgcn_global_load_lds(
                    (const __attribute__((address_space(1))) void*)(BC + basen*128 + tid*4),
                    (__attribute__((address_space(3))) void*)(sBC + tid*4), 16, 0, 0);
                __builtin_amdgcn_global_load_lds(
                    (const __attribute__((address_space(1))) void*)(xc + basen*E_ + tid*8),
                    (__attribute__((address_space(3))) void*)(sXC + tid*8), 16, 0, 0);
            }
        }
        __syncthreads();
    }
    size_t hb = ((size_t)(b*NC_ + c))*S_*E_ + d;
    #pragma unroll
    for (int q=0;q<4;q++)
        #pragma unroll
        for (int j=0;j<4;j++) H[hb + (size_t)(s0+q*4+j)*E_] = f2b(h4[q][j]);
}

// ---------------- scan pass 2: in-place carry combine on H -----------------
// after this, H[(b,c,s,d)] holds the carry (state entering chunk c)
__global__ __launch_bounds__(256) void carry_k(const float* __restrict__ dApT,
    us* H)
{
    int idx = blockIdx.x*256 + threadIdx.x;   // B_*S_*E_
    int d = idx & (E_-1); int s = (idx >> 8) & (S_-1); int b = idx >> 14;
    float ap = dApT[s*E_ + d];
    size_t base = ((size_t)(b*NC_))*S_*E_ + (size_t)s*E_ + d;
    float hh = 0.f;
    for (int c=0;c<NC_;c++){
        size_t p = base + (size_t)c*S_*E_;
        float hl = b2f(H[p]);
        H[p] = f2b(hh);
        hh = fmaf(ap, hh, hl);
    }
}

// ---------------- scan pass 3 + fused zin: grid B_*NC_ ---------------------
// c>0: y_final = ys + corr;  z = (y_final + D*xc)*silu(xres) -> XC
// c==0: elementwise z for chunk 0 (no correction), all threads, s4v.
__global__ __launch_bounds__(1024) void scan_fz(
    const float* __restrict__ dAT, const float* __restrict__ BC,
    const us* __restrict__ Hc, const us* __restrict__ ys,
    const us* xc, const us* __restrict__ xres,
    const float* __restrict__ Dp, us* zout)
{
    int b = blockIdx.x / NC_; int c = blockIdx.x % NC_;
    int tid = threadIdx.x;
    if (c == 0){
        size_t base = (size_t)b*T_*E_;        // t0 = 0; base multiple of E_
        for (int i = tid; i < (CL_*E_)/4; i += 1024){
            size_t e0 = base + (size_t)i*4;
            int d0 = (i*4) & (E_-1);
            s4v yv  = *(const s4v*)(ys + e0);
            s4v xcv = *(const s4v*)(xc + e0);
            s4v xrv = *(const s4v*)(xres + e0);
            f4v dv  = *(const f4v*)(Dp + d0);
            s4v o;
            #pragma unroll
            for (int j=0;j<4;j++){
                float y  = b2f((us)yv[j]) + dv[j] * b2f((us)xcv[j]);
                float xr = b2f((us)xrv[j]);
                o[j] = (short)f2b(y * (xr / (1.f + expf(-xr))));
            }
            *(s4v*)(zout + e0) = o;
        }
        return;
    }
    __shared__ float sC[TS_*64];
    int d = tid >> 2, sg = tid & 3, s0 = sg*16;
    f4v w4[4], dA4[4];
    size_t cb = ((size_t)(b*NC_ + c))*S_*E_ + d;
    #pragma unroll
    for (int q=0;q<4;q++){
        #pragma unroll
        for (int j=0;j<4;j++){
            int s = s0 + q*4 + j;
            dA4[q][j] = dAT[s*E_ + d];
            w4[q][j]  = dA4[q][j] * b2f(Hc[cb + (size_t)s*E_]);
        }
    }
    float Dd = Dp[d];
    int t0 = c*CL_;
    size_t base0 = (size_t)b*T_ + t0;
    if (tid < 400){
        __builtin_amdgcn_global_load_lds(
            (const __attribute__((address_space(1))) void*)(BC + (base0 + (tid>>4))*128 + 64 + (tid&15)*4),
            (__attribute__((address_space(3))) void*)(sC + tid*4), 16, 0, 0);
    }
    __syncthreads();
    for (int tile = 0; tile < NT_; ++tile){
        for (int st = 0; st < TS_; ++st){
            int t = t0 + tile*TS_ + st;
            const f4v* Cp = (const f4v*)(&sC[st*64 + s0]);
            f4v y4 = (f4v){0.f,0.f,0.f,0.f};
            #pragma unroll
            for (int q=0;q<4;q++){
                y4   = y4 + Cp[q]*w4[q];
                w4[q] = w4[q]*dA4[q];
            }
            float y = (y4[0]+y4[1]) + (y4[2]+y4[3]);
            y += __shfl_xor(y, 1, 4);
            y += __shfl_xor(y, 2, 4);
            if (sg == 0){
                size_t p = ((size_t)b*T_ + t)*E_ + d;
                float yf = b2f(ys[p]) + y;
                float xr = b2f(xres[p]);
                float z  = (yf + Dd * b2f(xc[p])) * (xr / (1.f + expf(-xr)));
                zout[p] = f2b(z);
            }
        }
        __syncthreads();
        if (tile+1 < NT_){
            size_t basen = base0 + (size_t)(tile+1)*TS_;
            if (tid < 400){
                __builtin_amdgcn_global_load_lds(
                    (const __attribute__((address_space(1))) void*)(BC + (basen + (tid>>4))*128 + 64 + (tid&15)*4),
                    (__attribute__((address_space(3))) void*)(sC + tid*4), 16, 0, 0);
            }
        }
        __syncthreads();
    }
}

// ---------------- layernorm bf16 (optional residual; out may alias z) ------
__global__ __launch_bounds__(256) void ln_k(const us* z,
    const us* __restrict__ resid, const float* __restrict__ g,
    const float* __restrict__ bb, us* out)
{
    int wid = threadIdx.x >> 6, lane = threadIdx.x & 63;
    size_t row = (size_t)blockIdx.x*4 + wid;
    size_t base = row*E_ + lane*4;
    s4v zv = *(const s4v*)(z + base);
    float v[4];
    #pragma unroll
    for (int j=0;j<4;j++) v[j] = b2f((us)zv[j]);
    if (resid){
        s4v rv = *(const s4v*)(resid + base);
        #pragma unroll
        for (int j=0;j<4;j++) v[j] += b2f((us)rv[j]);
    }
    float sum = v[0]+v[1]+v[2]+v[3];
    float sq  = v[0]*v[0]+v[1]*v[1]+v[2]*v[2]+v[3]*v[3];
    #pragma unroll
    for (int off=32; off>0; off>>=1){
        sum += __shfl_xor(sum, off, 64);
        sq  += __shfl_xor(sq,  off, 64);
    }
    float mean = sum * (1.f/E_);
    float var  = sq * (1.f/E_) - mean*mean;
    float rstd = rsqrtf(var + 1e-5f);
    f4v gv = *(const f4v*)(g + lane*4);
    f4v bv = *(const f4v*)(bb + lane*4);
    s4v o;
    #pragma unroll
    for (int j=0;j<4;j++)
        o[j] = (short)f2b((v[j]-mean)*rstd*gv[j] + bv[j]);
    *(s4v*)(out + base) = o;
}

// ---------------- layernorm f32 in / f32 out (in-place on d_out) -----------
__global__ __launch_bounds__(256) void ln_f32_k(const float* z,
    const float* __restrict__ g, const float* __restrict__ bb, float* out)
{
    int wid = threadIdx.x >> 6, lane = threadIdx.x & 63;
    size_t row = (size_t)blockIdx.x*4 + wid;
    size_t base = row*E_ + lane*4;
    f4v v = *(const f4v*)(z + base);
    float sum = v[0]+v[1]+v[2]+v[3];
    float sq  = v[0]*v[0]+v[1]*v[1]+v[2]*v[2]+v[3]*v[3];
    #pragma unroll
    for (int off=32; off>0; off>>=1){
        sum += __shfl_xor(sum, off, 64);
        sq  += __shfl_xor(sq,  off, 64);
    }
    float mean = sum * (1.f/E_);
    float var  = sq * (1.f/E_) - mean*mean;
    float rstd = rsqrtf(var + 1e-5f);
    f4v gv = *(const f4v*)(g + lane*4);
    f4v bv = *(const f4v*)(bb + lane*4);
    f4v o;
    #pragma unroll
    for (int j=0;j<4;j++)
        o[j] = (v[j]-mean)*rstd*gv[j] + bv[j];
    *(f4v*)(out + base) = o;
}

// ---------------- xpad: zero-padded (8 each side) copy of x0 ---------------
__global__ __launch_bounds__(256) void xpad_k(const us* __restrict__ x0,
    us* __restrict__ xp)
{
    int idx = blockIdx.x*256 + threadIdx.x;   // B_*TP_*32
    int dg = idx & 31; int r = idx >> 5;
    int tp = r % TP_; int b = r / TP_;
    s8v o;
    if (tp < 8 || tp >= T_+8){
        #pragma unroll
        for (int j=0;j<8;j++) o[j] = 0;
    } else {
        o = *(const s8v*)(x0 + ((size_t)b*T_ + tp - 8)*E_ + dg*8);
    }
    *(s8v*)(xp + (size_t)r*E_ + dg*8) = o;
}

// ---------------- probe: fires ONLY if final output is all-zero ------------
__global__ void probe_k(const unsigned int* __restrict__ outw,
    const us* p0, const us* p1, float* outf)
{
    if (threadIdx.x | blockIdx.x) return;
    bool zero = true;
    for (int i=0;i<512 && zero;i++)              if (outw[i]) zero = false;
    for (int i=2000000;i<2000512 && zero;i++)    if (outw[i]) zero = false;
    if (!zero) return;
    int code = 256, f;
    f=0; for (int i=0;i<256;i++) if (p0[i] & 0x7FFF) f=1;  code += 128*f;
    f=0; for (int i=0;i<256;i++) if (p1[i] & 0x7FFF) f=1;  code += 16*f;
    outf[0] = (float)code;
}

extern "C" void kernel_launch(void* const* d_in, const int* in_sizes, int n_in,
                              void* d_out, int out_size, void* d_ws, size_t ws_size,
                              hipStream_t stream)
{
    const int*   tokens   = (const int*)d_in[0];
    const float* tok_emb  = (const float*)d_in[1];
    const float* pos_emb  = (const float*)d_in[2];
    const float* in_w     = (const float*)d_in[3];
    const float* conv_w   = (const float*)d_in[4];
    const float* conv_b   = (const float*)d_in[5];
    const float* dt_w     = (const float*)d_in[6];
    const float* A_log    = (const float*)d_in[7];
    const float* D_param  = (const float*)d_in[8];
    const float* B_w      = (const float*)d_in[9];
    const float* C_w      = (const float*)d_in[10];
    const float* out_w    = (const float*)d_in[11];
    const float* ln_g     = (const float*)d_in[12];
    const float* ln_b     = (const float*)d_in[13];
    const float* ctx_w    = (const float*)d_in[14];
    const float* ctx_b    = (const float*)d_in[15];
    const float* fus_w    = (const float*)d_in[16];
    const float* fus_b    = (const float*)d_in[17];
    const float* fus_ln_g = (const float*)d_in[18];
    const float* fus_ln_b = (const float*)d_in[19];

    char* ws = (char*)d_ws;
    size_t off = 0;
    auto alloc = [&](size_t bytes){ size_t o = off; off += (bytes + 255) & ~(size_t)255; return o; };
    const size_t BT = BT_;
    size_t o_p0  = alloc(BT*E_*2);
    size_t o_p1  = alloc(BT*E_*2);
    size_t o_ctx = alloc(BT*E_*2);
    size_t o_xin = alloc(BT*E_*2);          // XIN / Y2 / (XPAD spills into o_xc)
    size_t o_xc  = alloc(BT*E_*2);          // XC / ZIN
    size_t o_bc  = alloc(BT*128*4);         // fused B|C f32
    size_t o_h   = alloc((size_t)B_*NC_*S_*E_*2);
    size_t o_wp  = alloc((size_t)4*64*768*2);
    size_t o_wi  = alloc((size_t)L_*2*E_*E_*2);
    size_t o_wo  = alloc((size_t)L_*E_*E_*2);
    size_t o_wbc = alloc((size_t)L_*128*E_*2);
    size_t o_wf  = alloc((size_t)E_*2*E_*2);
    size_t o_dtv = alloc(E_*4);
    size_t o_dat = alloc(E_*S_*4);
    size_t o_dap = alloc(E_*S_*4);
    (void)ws_size; (void)in_sizes; (void)n_in; (void)out_size;

    us* P0   = (us*)(ws + o_p0);
    us* P1   = (us*)(ws + o_p1);
    us* CTXB = (us*)(ws + o_ctx);
    us* XIN  = (us*)(ws + o_xin);
    us* XC   = (us*)(ws + o_xc);
    float* BCf = (float*)(ws + o_bc);
    us* Hb   = (us*)(ws + o_h);
    us* WP   = (us*)(ws + o_wp);
    us* WI   = (us*)(ws + o_wi);
    us* WO   = (us*)(ws + o_wo);
    us* WBC  = (us*)(ws + o_wbc);
    us* WF   = (us*)(ws + o_wf);
    float* DTV  = (float*)(ws + o_dtv);
    float* DAT  = (float*)(ws + o_dat);
    float* DAPT = (float*)(ws + o_dap);
    us* XPAD = XIN;                    // phase A only
    us* YS   = (us*)d_out;             // bf16 scratch: first half of f32 d_out
    us* XRES = (us*)d_out + BT*E_;     // bf16 scratch: second half of d_out
    // (fusion GEMM overwrites all of d_out after the layers)

    // ---- weight packing (f32 -> bf16) ----
    cvtw_k<<<L_*2*E_*E_/1024, 256, 0, stream>>>(in_w,  WI);
    cvtw_k<<<L_*E_*E_/1024,   256, 0, stream>>>(out_w, WO);
    cvtw_k<<<E_*2*E_/1024,    256, 0, stream>>>(fus_w, WF);
    packbc_k<<<L_*128*E_/256, 256, 0, stream>>>(B_w, C_w, WBC);
    packw_k<<<4*64*768/256,   256, 0, stream>>>(ctx_w, WP);

    // ---- embedding ----
    embed_k<<<BT_*32/256, 256, 0, stream>>>(tokens, tok_emb, pos_emb, P0);

    // ---- context path: 4 dilations in ONE launch (blockIdx.y = j) ----
    xpad_k<<<B_*TP_*32/256, 256, 0, stream>>>(P0, XPAD);
    gemm_k<4,5,64><<<dim3(BT_/BM, 4), 256, 0, stream>>>(
        XPAD, nullptr, E_, 0, WP, 768,
        CTXB, nullptr, ctx_b, E_, 768);

    // ---- SSM layers ----
    for (int l = 0; l < L_; ++l){
        const us* xprev = (l==1) ? P1 : P0;
        us*       xnext = (l==1) ? P0 : P1;

        lconst_k<<<E_*S_/256, 256, 0, stream>>>(dt_w + (size_t)l*E_, A_log + (size_t)l*E_*S_,
                                                DTV, DAT, DAPT);
        // fused in-proj: N=512, split store -> XIN (in1) + XRES
        gemm_k<0,1,128><<<dim3(BT_/BM, 4), 256, 0, stream>>>(
            xprev, nullptr, E_, 0, WI + (size_t)l*2*E_*E_, E_, XIN, XRES, nullptr, E_, E_);
        dwconv_k<<<BT_*32/256, 256, 0, stream>>>(XIN, conv_w + (size_t)l*E_*4, conv_b + (size_t)l*E_, XC);
        gemm_k<0,2,128><<<dim3(BT_/BM, 1), 256, 0, stream>>>(
            XC, nullptr, E_, 0, WBC + (size_t)l*128*E_, E_, BCf, nullptr, nullptr, 128, E_);
        scan_ly<<<B_*NC_, 1024, 0, stream>>>(DAT, DTV, XC, BCf, YS, Hb);
        carry_k<<<B_*S_*E_/256, 256, 0, stream>>>(DAPT, Hb);
        // fused correction + zin -> XC in place
        scan_fz<<<B_*NC_, 1024, 0, stream>>>(DAT, BCf, Hb, YS, XC, XRES,
                                             D_param + (size_t)l*E_, XC);
        gemm_k<0,0,128><<<dim3(BT_/BM, 2), 256, 0, stream>>>(
            XC, nullptr, E_, 0, WO + (size_t)l*E_*E_, E_, XIN /*y2*/, nullptr, nullptr, E_, E_);
        ln_k<<<BT_/4, 256, 0, stream>>>(XIN, xprev, ln_g + (size_t)l*E_, ln_b + (size_t)l*E_, xnext);
    }

    // ---- fusion: relu(concat([feats, ctx]) @ fus_w.T + fus_b) -> f32 d_out
    gemm_k<2,6,128><<<dim3(BT_/BM, 2), 256, 0, stream>>>(
        P1, CTXB, E_, 0, WF, 2*E_, d_out, nullptr, fus_b, E_, 2*E_);
    // ---- final layernorm, f32 in place on d_out ----
    ln_f32_k<<<BT_/4, 256, 0, stream>>>((const float*)d_out, fus_ln_g, fus_ln_b, (float*)d_out);

    // ---- probe: only writes if final output is all-zero (dead pipeline) ----
    probe_k<<<1, 64, 0, stream>>>((const unsigned int*)d_out, P0, P1, (float*)d_out);
}

// Round 20
// 1326.318 us; speedup vs baseline: 1.1421x; 1.1421x over previous
//
#include <hip/hip_runtime.h>
#include <stdint.h>

#define B_ 32
#define T_ 2000
#define E_ 256
#define S_ 64
#define L_ 3
#define BT_ (B_*T_)
#define NC_ 16
#define CL_ 125
#define TS_ 25
#define NT_ (CL_/TS_)
#define TP_ (T_+16)

typedef short s8v __attribute__((ext_vector_type(8)));
typedef short s4v __attribute__((ext_vector_type(4)));
typedef float f4v __attribute__((ext_vector_type(4)));
typedef float f2v __attribute__((ext_vector_type(2)));
typedef unsigned short us;

__device__ __forceinline__ float b2f(us u){
    return __uint_as_float(((unsigned int)u) << 16);
}
__device__ __forceinline__ us f2b(float f){
    unsigned int x = __float_as_uint(f);
    x += 0x7fffu + ((x >> 16) & 1u);   // RNE
    return (us)(x >> 16);
}

// ---------------- f32 -> bf16 weight pack (4 elems/thread, exact grids) ----
__global__ __launch_bounds__(256) void cvtw_k(const float* __restrict__ src,
    us* __restrict__ dst)
{
    int idx = blockIdx.x*256 + threadIdx.x;
    f4v v = *(const f4v*)(src + (size_t)idx*4);
    s4v o;
    #pragma unroll
    for (int j=0;j<4;j++) o[j] = (short)f2b(v[j]);
    *(s4v*)(dst + (size_t)idx*4) = o;
}

// ---------------- pack B_w|C_w -> WBC[l][128][256] bf16 --------------------
__global__ __launch_bounds__(256) void packbc_k(const float* __restrict__ Bw,
    const float* __restrict__ Cw, us* __restrict__ wbc)
{
    int idx = blockIdx.x*256 + threadIdx.x;   // L_*128*256
    int i = idx & 255; int r = (idx >> 8) & 127; int l = idx >> 15;
    const float* src = (r < 64) ? (Bw + ((size_t)l*S_ + r)*E_ + i)
                                : (Cw + ((size_t)l*S_ + (r-64))*E_ + i);
    wbc[idx] = f2b(*src);
}

// ---------------- pack ctx_w (j,c,i,tap) f32 -> wp[j][c][tap*256+i] bf16 ---
__global__ __launch_bounds__(256) void packw_k(const float* __restrict__ cw,
    us* __restrict__ wp)
{
    int idx = blockIdx.x*256 + threadIdx.x;   // 4*64*768
    int i2 = idx % 768; int r = idx / 768;
    int c = r & 63; int j = r >> 6;
    int tap = i2 >> 8; int i = i2 & 255;
    wp[idx] = f2b(cw[(((size_t)(j*64 + c))*E_ + i)*3 + tap]);
}

// ---------------- embedding: x0 = bf16(tok_emb[tok] + pos_emb[t]) ----------
__global__ __launch_bounds__(256) void embed_k(const int* __restrict__ tok,
    const float* __restrict__ te, const float* __restrict__ pe, us* __restrict__ x0)
{
    int idx = blockIdx.x*256 + threadIdx.x;      // BT_*32
    int dg = idx & 31; int bt = idx >> 5; int t = bt % T_;
    int tk = tok[bt] & 255;                      // V=256
    const float* ta = te + (size_t)tk*E_ + dg*8;
    const float* pa = pe + (size_t)t*E_ + dg*8;
    f4v a0 = *(const f4v*)ta, a1 = *(const f4v*)(ta+4);
    f4v p0 = *(const f4v*)pa, p1 = *(const f4v*)(pa+4);
    s8v o;
    #pragma unroll
    for (int j=0;j<4;j++){
        o[j]   = (short)f2b(a0[j] + p0[j]);
        o[j+4] = (short)f2b(a1[j] + p1[j]);
    }
    *(s8v*)(x0 + (size_t)bt*E_ + dg*8) = o;
}

// ---------------- per-layer constants: dt, dA^T, (dA^CL)^T -----------------
__global__ __launch_bounds__(256) void lconst_k(const float* __restrict__ dt_w,
    const float* __restrict__ A_log, float* __restrict__ dtv,
    float* __restrict__ dAT, float* __restrict__ dApT)
{
    int idx = blockIdx.x*256 + threadIdx.x;      // E_*S_
    int d = idx & (E_-1); int s = idx >> 8;
    float dt = log1pf(expf(dt_w[d]));            // softplus
    float A  = -expf(A_log[d*S_ + s]);
    float dA = 1.f + dt*A;
    dAT[s*E_ + d]  = dA;
    dApT[s*E_ + d] = powf(dA, (float)CL_);
    if (s == 0) dtv[d] = dt;
}

// ---------------- depthwise causal conv(4) + bias + SiLU -------------------
__global__ __launch_bounds__(256) void dwconv_k(const us* __restrict__ xin,
    const float* __restrict__ cw, const float* __restrict__ cb, us* __restrict__ xc)
{
    int idx = blockIdx.x*256 + threadIdx.x;      // BT_*32
    int dg = idx & 31; int bt = idx >> 5; int t = bt % T_;
    int d0 = dg*8;
    float acc[8]; float w[8][4];
    #pragma unroll
    for (int j=0;j<8;j++){
        f4v wv = *(const f4v*)(cw + (size_t)(d0+j)*4);
        #pragma unroll
        for (int k=0;k<4;k++) w[j][k] = wv[k];
        acc[j] = cb[d0+j];
    }
    #pragma unroll
    for (int k=0;k<4;k++){
        if (t + k - 3 >= 0){
            s8v xv = *(const s8v*)(xin + (size_t)(bt + k - 3)*E_ + d0);
            #pragma unroll
            for (int j=0;j<8;j++) acc[j] = fmaf(b2f((us)xv[j]), w[j][k], acc[j]);
        }
    }
    s8v o;
    #pragma unroll
    for (int j=0;j<8;j++){ float v = acc[j]; v = v / (1.f + expf(-v)); o[j] = (short)f2b(v); }
    *(s8v*)(xc + (size_t)bt*E_ + d0) = o;
}

// ---------------- MFMA GEMM: C[m,n] = sum_k A[m,k]*W[n,k] ------------------
// BNT = 64 or 128 (block tile is BM x BNT, 4 waves as 2x2 over 64 x BNT/2)
// AMODE 0: A1+m*lda+k | 2: concat(A1,A2) | 4: ctx taps, shift=1<<blockIdx.y
// EPI 0: bf16 | 1: split cols 256/256 -> C1,C2 bf16 | 2: f32 plain
//     5: +bias bf16 | 6: +bias relu f32
#define BM 128
#define BK 32

template<int AMODE, int EPI, int BNT>
__global__ __launch_bounds__(256)
void gemm_k(const us* __restrict__ A1, const us* __restrict__ A2,
            int lda, int shift,
            const us* __restrict__ W, int ldw,
            void* __restrict__ C1, void* __restrict__ C2,
            const float* __restrict__ bias,
            int ldc, int K)
{
    constexpr int NR = BNT/32;                 // 2 (BNT=64) or 4 (BNT=128)
    __shared__ us Al[BM*BK];                   // seg-linear: elem=(row*4+ks)*8
    __shared__ us Bl[BNT*BK];
    const int tid = threadIdx.x;
    const int wid = tid >> 6, lane = tid & 63;
    const int m0 = blockIdx.x * BM;
    const int n0 = blockIdx.y * BNT;
    const int wr = wid >> 1, wc = wid & 1;
    int sh = shift;
    if constexpr (AMODE==4) sh = 1 << blockIdx.y;
    f4v acc[4][NR];
    #pragma unroll
    for (int a=0;a<4;a++)
        #pragma unroll
        for (int b=0;b<NR;b++) acc[a][b] = (f4v){0.f,0.f,0.f,0.f};

    for (int k0 = 0; k0 < K; k0 += BK){
        if (k0) __syncthreads();               // prev tile's readers done
        #pragma unroll
        for (int i=0;i<2;i++){
            int g = i*256 + tid;               // 0..511
            int row = g >> 2, ks = g & 3;
            const us* src;
            if constexpr (AMODE==0){
                src = A1 + (size_t)(m0+row)*lda + k0 + ks*8;
            } else if constexpr (AMODE==2){
                int kk = k0 + ks*8;
                const us* base = (kk < E_) ? A1 : A2;
                src = base + (size_t)(m0+row)*E_ + (kk & (E_-1));
            } else {
                int kk = k0 + ks*8;
                int tap = kk >> 8; int kin = kk & (E_-1);
                int m = m0 + row; int bb = m / T_; int tt = m - bb*T_;
                src = A1 + ((size_t)bb*TP_ + 8 + tt + (tap-1)*sh)*E_ + kin;
            }
            __builtin_amdgcn_global_load_lds(
                (const __attribute__((address_space(1))) void*)src,
                (__attribute__((address_space(3))) void*)(Al + (size_t)g*8), 16, 0, 0);
        }
        #pragma unroll
        for (int i=0;i<BNT/64;i++){
            int g = i*256 + tid;
            int row = g >> 2, ks = g & 3;
            const us* src = W + (size_t)(n0+row)*ldw + k0 + ks*8;
            __builtin_amdgcn_global_load_lds(
                (const __attribute__((address_space(1))) void*)src,
                (__attribute__((address_space(3))) void*)(Bl + (size_t)g*8), 16, 0, 0);
        }
        __syncthreads();                       // vmcnt(0) drained before barrier

        s8v af[4], bfr[NR];
        #pragma unroll
        for (int mr=0;mr<4;mr++)
            af[mr] = *(const s8v*)(Al + ((size_t)(wr*64 + mr*16 + (lane&15))*4 + (lane>>4))*8);
        #pragma unroll
        for (int nr=0;nr<NR;nr++)
            bfr[nr] = *(const s8v*)(Bl + ((size_t)(wc*(BNT/2) + nr*16 + (lane&15))*4 + (lane>>4))*8);
        #pragma unroll
        for (int mr=0;mr<4;mr++)
            #pragma unroll
            for (int nr=0;nr<NR;nr++)
                acc[mr][nr] = __builtin_amdgcn_mfma_f32_16x16x32_bf16(af[mr], bfr[nr], acc[mr][nr], 0, 0, 0);
    }
    #pragma unroll
    for (int mr=0;mr<4;mr++){
        #pragma unroll
        for (int nr=0;nr<NR;nr++){
            int col = n0 + wc*(BNT/2) + nr*16 + (lane & 15);
            int rb  = m0 + wr*64 + mr*16 + ((lane >> 4) << 2);
            #pragma unroll
            for (int i=0;i<4;i++){
                float val = acc[mr][nr][i];
                size_t row = (size_t)(rb + i);
                if constexpr (EPI==0){
                    ((us*)C1)[row*ldc + col] = f2b(val);
                } else if constexpr (EPI==1){
                    if (col < E_) ((us*)C1)[row*E_ + col] = f2b(val);
                    else          ((us*)C2)[row*E_ + (col - E_)] = f2b(val);
                } else if constexpr (EPI==2){
                    ((float*)C1)[row*ldc + col] = val;
                } else if constexpr (EPI==5){
                    val += bias[col];
                    ((us*)C1)[row*ldc + col] = f2b(val);
                } else {                      // EPI==6: f32 out, bias+relu
                    val += bias[col];
                    val = fmaxf(val, 0.f);
                    ((float*)C1)[row*ldc + col] = val;
                }
            }
        }
    }
}

// ---------------- scan pass 1: local recurrence, ys + final-h --------------
// 1024 thr (tid = d*4+sg, 16 states each); CL=125, TS=25; tiles staged via
// global_load_lds (BC/xc tiles contiguous; 800 issuing threads).
__global__ __launch_bounds__(1024) void scan_ly(
    const float* __restrict__ dAT, const float* __restrict__ dtv,
    const us* __restrict__ xc, const float* __restrict__ BC,
    us* __restrict__ ys, us* __restrict__ H)
{
    __shared__ float sBC[TS_*128];     // 12.8 KB
    __shared__ us    sXC[TS_*256];     // 12.8 KB
    int b = blockIdx.x / NC_, c = blockIdx.x % NC_;
    int tid = threadIdx.x;
    int d = tid >> 2, sg = tid & 3, s0 = sg*16;
    f4v h4[4], dA4[4];
    #pragma unroll
    for (int q=0;q<4;q++){
        #pragma unroll
        for (int j=0;j<4;j++){ h4[q][j] = 0.f; dA4[q][j] = dAT[(s0+q*4+j)*E_ + d]; }
    }
    float dtd = dtv[d];
    int t0 = c*CL_;
    size_t base0 = (size_t)b*T_ + t0;
    if (tid < 800){
        __builtin_amdgcn_global_load_lds(
            (const __attribute__((address_space(1))) void*)(BC + base0*128 + tid*4),
            (__attribute__((address_space(3))) void*)(sBC + tid*4), 16, 0, 0);
        __builtin_amdgcn_global_load_lds(
            (const __attribute__((address_space(1))) void*)(xc + base0*E_ + tid*8),
            (__attribute__((address_space(3))) void*)(sXC + tid*8), 16, 0, 0);
    }
    __syncthreads();
    for (int tile = 0; tile < NT_; ++tile){
        for (int st = 0; st < TS_; ++st){
            int t = t0 + tile*TS_ + st;
            float u = dtd * b2f(sXC[st*256 + d]);
            const f4v* Bp = (const f4v*)(&sBC[st*128 + s0]);
            const f4v* Cp = (const f4v*)(&sBC[st*128 + 64 + s0]);
            f4v y4 = (f4v){0.f,0.f,0.f,0.f};
            #pragma unroll
            for (int q=0;q<4;q++){
                h4[q] = dA4[q]*h4[q] + Bp[q]*u;
                y4    = y4 + Cp[q]*h4[q];
            }
            float y = (y4[0]+y4[1]) + (y4[2]+y4[3]);
            y += __shfl_xor(y, 1, 4);
            y += __shfl_xor(y, 2, 4);
            if (sg == 0) ys[((size_t)b*T_ + t)*E_ + d] = f2b(y);
        }
        __syncthreads();
        if (tile+1 < NT_){
            size_t basen = base0 + (size_t)(tile+1)*TS_;
            if (tid < 800){
                __builtin_amdgcn_global_load_lds(
                    (const __attribute__((address_space(1))) void*)(BC + basen*128 + tid*4),
                    (__attribute__((address_space(3))) void*)(sBC + tid*4), 16, 0, 0);
                __builtin_amdgcn_global_load_lds(
                    (const __attribute__((address_space(1))) void*)(xc + basen*E_ + tid*8),
                    (__attribute__((address_space(3))) void*)(sXC + tid*8), 16, 0, 0);
            }
        }
        __syncthreads();
    }
    size_t hb = ((size_t)(b*NC_ + c))*S_*E_ + d;
    #pragma unroll
    for (int q=0;q<4;q++)
        #pragma unroll
        for (int j=0;j<4;j++) H[hb + (size_t)(s0+q*4+j)*E_] = f2b(h4[q][j]);
}

// ---------------- scan pass 2: in-place carry combine on H -----------------
// after this, H[(b,c,s,d)] holds the carry (state entering chunk c)
__global__ __launch_bounds__(256) void carry_k(const float* __restrict__ dApT,
    us* H)
{
    int idx = blockIdx.x*256 + threadIdx.x;   // B_*S_*E_
    int d = idx & (E_-1); int s = (idx >> 8) & (S_-1); int b = idx >> 14;
    float ap = dApT[s*E_ + d];
    size_t base = ((size_t)(b*NC_))*S_*E_ + (size_t)s*E_ + d;
    float hh = 0.f;
    for (int c=0;c<NC_;c++){
        size_t p = base + (size_t)c*S_*E_;
        float hl = b2f(H[p]);
        H[p] = f2b(hh);
        hh = fmaf(ap, hh, hl);
    }
}

// ---------------- scan pass 3: correction, chunks 1..NC-1 ------------------
// y_corr(t) = sum_s C[t,s] * dA[s]^(t-t0+1) * h_in[s];  ys += y_corr.
// Stages only the C-half (6.4KB f32 / tile) via global_load_lds (400 thr).
__global__ __launch_bounds__(1024) void scan_fx(
    const float* __restrict__ dAT, const float* __restrict__ BC,
    const us* __restrict__ Hc, us* ys)
{
    __shared__ float sC[TS_*64];
    int b = blockIdx.x / (NC_-1); int c = 1 + blockIdx.x % (NC_-1);
    int tid = threadIdx.x;
    int d = tid >> 2, sg = tid & 3, s0 = sg*16;
    f4v w4[4], dA4[4];
    size_t cb = ((size_t)(b*NC_ + c))*S_*E_ + d;
    #pragma unroll
    for (int q=0;q<4;q++){
        #pragma unroll
        for (int j=0;j<4;j++){
            int s = s0 + q*4 + j;
            dA4[q][j] = dAT[s*E_ + d];
            w4[q][j]  = dA4[q][j] * b2f(Hc[cb + (size_t)s*E_]);
        }
    }
    int t0 = c*CL_;
    size_t base0 = (size_t)b*T_ + t0;
    if (tid < 400){
        __builtin_amdgcn_global_load_lds(
            (const __attribute__((address_space(1))) void*)(BC + (base0 + (tid>>4))*128 + 64 + (tid&15)*4),
            (__attribute__((address_space(3))) void*)(sC + tid*4), 16, 0, 0);
    }
    __syncthreads();
    for (int tile = 0; tile < NT_; ++tile){
        for (int st = 0; st < TS_; ++st){
            int t = t0 + tile*TS_ + st;
            const f4v* Cp = (const f4v*)(&sC[st*64 + s0]);
            f4v y4 = (f4v){0.f,0.f,0.f,0.f};
            #pragma unroll
            for (int q=0;q<4;q++){
                y4   = y4 + Cp[q]*w4[q];
                w4[q] = w4[q]*dA4[q];
            }
            float y = (y4[0]+y4[1]) + (y4[2]+y4[3]);
            y += __shfl_xor(y, 1, 4);
            y += __shfl_xor(y, 2, 4);
            if (sg == 0){
                size_t p = ((size_t)b*T_ + t)*E_ + d;
                ys[p] = f2b(b2f(ys[p]) + y);
            }
        }
        __syncthreads();
        if (tile+1 < NT_){
            size_t basen = base0 + (size_t)(tile+1)*TS_;
            if (tid < 400){
                __builtin_amdgcn_global_load_lds(
                    (const __attribute__((address_space(1))) void*)(BC + (basen + (tid>>4))*128 + 64 + (tid&15)*4),
                    (__attribute__((address_space(3))) void*)(sC + tid*4), 16, 0, 0);
            }
        }
        __syncthreads();
    }
}

// ---------------- gating: zout = (ys + D*xc) * silu(xres) (zout==xc ok) ----
__global__ __launch_bounds__(256) void zin_k(const us* __restrict__ ys,
    const us* xc, const us* __restrict__ xres,
    const float* __restrict__ Dp, us* zout)
{
    size_t e0 = ((size_t)blockIdx.x*256 + threadIdx.x)*4;   // BT_*E_/4 threads
    int d0 = (int)(e0 & (E_-1));
    s4v yv  = *(const s4v*)(ys + e0);
    s4v xcv = *(const s4v*)(xc + e0);
    s4v xrv = *(const s4v*)(xres + e0);
    f4v dv  = *(const f4v*)(Dp + d0);
    s4v o;
    #pragma unroll
    for (int j=0;j<4;j++){
        float y  = b2f((us)yv[j]) + dv[j] * b2f((us)xcv[j]);
        float xr = b2f((us)xrv[j]);
        o[j] = (short)f2b(y * (xr / (1.f + expf(-xr))));
    }
    *(s4v*)(zout + e0) = o;
}

// ---------------- layernorm bf16 (optional residual; out may alias z) ------
__global__ __launch_bounds__(256) void ln_k(const us* z,
    const us* __restrict__ resid, const float* __restrict__ g,
    const float* __restrict__ bb, us* out)
{
    int wid = threadIdx.x >> 6, lane = threadIdx.x & 63;
    size_t row = (size_t)blockIdx.x*4 + wid;
    size_t base = row*E_ + lane*4;
    s4v zv = *(const s4v*)(z + base);
    float v[4];
    #pragma unroll
    for (int j=0;j<4;j++) v[j] = b2f((us)zv[j]);
    if (resid){
        s4v rv = *(const s4v*)(resid + base);
        #pragma unroll
        for (int j=0;j<4;j++) v[j] += b2f((us)rv[j]);
    }
    float sum = v[0]+v[1]+v[2]+v[3];
    float sq  = v[0]*v[0]+v[1]*v[1]+v[2]*v[2]+v[3]*v[3];
    #pragma unroll
    for (int off=32; off>0; off>>=1){
        sum += __shfl_xor(sum, off, 64);
        sq  += __shfl_xor(sq,  off, 64);
    }
    float mean = sum * (1.f/E_);
    float var  = sq * (1.f/E_) - mean*mean;
    float rstd = rsqrtf(var + 1e-5f);
    f4v gv = *(const f4v*)(g + lane*4);
    f4v bv = *(const f4v*)(bb + lane*4);
    s4v o;
    #pragma unroll
    for (int j=0;j<4;j++)
        o[j] = (short)f2b((v[j]-mean)*rstd*gv[j] + bv[j]);
    *(s4v*)(out + base) = o;
}

// ---------------- layernorm f32 in / f32 out (in-place on d_out) -----------
__global__ __launch_bounds__(256) void ln_f32_k(const float* z,
    const float* __restrict__ g, const float* __restrict__ bb, float* out)
{
    int wid = threadIdx.x >> 6, lane = threadIdx.x & 63;
    size_t row = (size_t)blockIdx.x*4 + wid;
    size_t base = row*E_ + lane*4;
    f4v v = *(const f4v*)(z + base);
    float sum = v[0]+v[1]+v[2]+v[3];
    float sq  = v[0]*v[0]+v[1]*v[1]+v[2]*v[2]+v[3]*v[3];
    #pragma unroll
    for (int off=32; off>0; off>>=1){
        sum += __shfl_xor(sum, off, 64);
        sq  += __shfl_xor(sq,  off, 64);
    }
    float mean = sum * (1.f/E_);
    float var  = sq * (1.f/E_) - mean*mean;
    float rstd = rsqrtf(var + 1e-5f);
    f4v gv = *(const f4v*)(g + lane*4);
    f4v bv = *(const f4v*)(bb + lane*4);
    f4v o;
    #pragma unroll
    for (int j=0;j<4;j++)
        o[j] = (v[j]-mean)*rstd*gv[j] + bv[j];
    *(f4v*)(out + base) = o;
}

// ---------------- xpad: zero-padded (8 each side) copy of x0 ---------------
__global__ __launch_bounds__(256) void xpad_k(const us* __restrict__ x0,
    us* __restrict__ xp)
{
    int idx = blockIdx.x*256 + threadIdx.x;   // B_*TP_*32
    int dg = idx & 31; int r = idx >> 5;
    int tp = r % TP_; int b = r / TP_;
    s8v o;
    if (tp < 8 || tp >= T_+8){
        #pragma unroll
        for (int j=0;j<8;j++) o[j] = 0;
    } else {
        o = *(const s8v*)(x0 + ((size_t)b*T_ + tp - 8)*E_ + dg*8);
    }
    *(s8v*)(xp + (size_t)r*E_ + dg*8) = o;
}

// ---------------- probe: fires ONLY if final output is all-zero ------------
__global__ void probe_k(const unsigned int* __restrict__ outw,
    const us* p0, const us* p1, float* outf)
{
    if (threadIdx.x | blockIdx.x) return;
    bool zero = true;
    for (int i=0;i<512 && zero;i++)              if (outw[i]) zero = false;
    for (int i=2000000;i<2000512 && zero;i++)    if (outw[i]) zero = false;
    if (!zero) return;
    int code = 256, f;
    f=0; for (int i=0;i<256;i++) if (p0[i] & 0x7FFF) f=1;  code += 128*f;
    f=0; for (int i=0;i<256;i++) if (p1[i] & 0x7FFF) f=1;  code += 16*f;
    outf[0] = (float)code;
}

extern "C" void kernel_launch(void* const* d_in, const int* in_sizes, int n_in,
                              void* d_out, int out_size, void* d_ws, size_t ws_size,
                              hipStream_t stream)
{
    const int*   tokens   = (const int*)d_in[0];
    const float* tok_emb  = (const float*)d_in[1];
    const float* pos_emb  = (const float*)d_in[2];
    const float* in_w     = (const float*)d_in[3];
    const float* conv_w   = (const float*)d_in[4];
    const float* conv_b   = (const float*)d_in[5];
    const float* dt_w     = (const float*)d_in[6];
    const float* A_log    = (const float*)d_in[7];
    const float* D_param  = (const float*)d_in[8];
    const float* B_w      = (const float*)d_in[9];
    const float* C_w      = (const float*)d_in[10];
    const float* out_w    = (const float*)d_in[11];
    const float* ln_g     = (const float*)d_in[12];
    const float* ln_b     = (const float*)d_in[13];
    const float* ctx_w    = (const float*)d_in[14];
    const float* ctx_b    = (const float*)d_in[15];
    const float* fus_w    = (const float*)d_in[16];
    const float* fus_b    = (const float*)d_in[17];
    const float* fus_ln_g = (const float*)d_in[18];
    const float* fus_ln_b = (const float*)d_in[19];

    char* ws = (char*)d_ws;
    size_t off = 0;
    auto alloc = [&](size_t bytes){ size_t o = off; off += (bytes + 255) & ~(size_t)255; return o; };
    const size_t BT = BT_;
    size_t o_p0  = alloc(BT*E_*2);
    size_t o_p1  = alloc(BT*E_*2);
    size_t o_ctx = alloc(BT*E_*2);
    size_t o_xin = alloc(BT*E_*2);          // XIN / Y2 / (XPAD spills into o_xc)
    size_t o_xc  = alloc(BT*E_*2);          // XC / ZIN
    size_t o_bc  = alloc(BT*128*4);         // fused B|C f32
    size_t o_h   = alloc((size_t)B_*NC_*S_*E_*2);
    size_t o_wp  = alloc((size_t)4*64*768*2);
    size_t o_wi  = alloc((size_t)L_*2*E_*E_*2);
    size_t o_wo  = alloc((size_t)L_*E_*E_*2);
    size_t o_wbc = alloc((size_t)L_*128*E_*2);
    size_t o_wf  = alloc((size_t)E_*2*E_*2);
    size_t o_dtv = alloc(E_*4);
    size_t o_dat = alloc(E_*S_*4);
    size_t o_dap = alloc(E_*S_*4);
    (void)ws_size; (void)in_sizes; (void)n_in; (void)out_size;

    us* P0   = (us*)(ws + o_p0);
    us* P1   = (us*)(ws + o_p1);
    us* CTXB = (us*)(ws + o_ctx);
    us* XIN  = (us*)(ws + o_xin);
    us* XC   = (us*)(ws + o_xc);
    float* BCf = (float*)(ws + o_bc);
    us* Hb   = (us*)(ws + o_h);
    us* WP   = (us*)(ws + o_wp);
    us* WI   = (us*)(ws + o_wi);
    us* WO   = (us*)(ws + o_wo);
    us* WBC  = (us*)(ws + o_wbc);
    us* WF   = (us*)(ws + o_wf);
    float* DTV  = (float*)(ws + o_dtv);
    float* DAT  = (float*)(ws + o_dat);
    float* DAPT = (float*)(ws + o_dap);
    us* XPAD = XIN;                    // phase A only
    us* YS   = (us*)d_out;             // bf16 scratch: first half of f32 d_out
    us* XRES = (us*)d_out + BT*E_;     // bf16 scratch: second half of d_out
    // (fusion GEMM overwrites all of d_out after the layers)

    // ---- weight packing (f32 -> bf16) ----
    cvtw_k<<<L_*2*E_*E_/1024, 256, 0, stream>>>(in_w,  WI);
    cvtw_k<<<L_*E_*E_/1024,   256, 0, stream>>>(out_w, WO);
    cvtw_k<<<E_*2*E_/1024,    256, 0, stream>>>(fus_w, WF);
    packbc_k<<<L_*128*E_/256, 256, 0, stream>>>(B_w, C_w, WBC);
    packw_k<<<4*64*768/256,   256, 0, stream>>>(ctx_w, WP);

    // ---- embedding ----
    embed_k<<<BT_*32/256, 256, 0, stream>>>(tokens, tok_emb, pos_emb, P0);

    // ---- context path: 4 dilations in ONE launch (blockIdx.y = j) ----
    xpad_k<<<B_*TP_*32/256, 256, 0, stream>>>(P0, XPAD);
    gemm_k<4,5,64><<<dim3(BT_/BM, 4), 256, 0, stream>>>(
        XPAD, nullptr, E_, 0, WP, 768,
        CTXB, nullptr, ctx_b, E_, 768);

    // ---- SSM layers ----
    for (int l = 0; l < L_; ++l){
        const us* xprev = (l==1) ? P1 : P0;
        us*       xnext = (l==1) ? P0 : P1;

        lconst_k<<<E_*S_/256, 256, 0, stream>>>(dt_w + (size_t)l*E_, A_log + (size_t)l*E_*S_,
                                                DTV, DAT, DAPT);
        // fused in-proj: N=512, split store -> XIN (in1) + XRES
        gemm_k<0,1,128><<<dim3(BT_/BM, 4), 256, 0, stream>>>(
            xprev, nullptr, E_, 0, WI + (size_t)l*2*E_*E_, E_, XIN, XRES, nullptr, E_, E_);
        dwconv_k<<<BT_*32/256, 256, 0, stream>>>(XIN, conv_w + (size_t)l*E_*4, conv_b + (size_t)l*E_, XC);
        gemm_k<0,2,128><<<dim3(BT_/BM, 1), 256, 0, stream>>>(
            XC, nullptr, E_, 0, WBC + (size_t)l*128*E_, E_, BCf, nullptr, nullptr, 128, E_);
        scan_ly<<<B_*NC_, 1024, 0, stream>>>(DAT, DTV, XC, BCf, YS, Hb);
        carry_k<<<B_*S_*E_/256, 256, 0, stream>>>(DAPT, Hb);
        scan_fx<<<B_*(NC_-1), 1024, 0, stream>>>(DAT, BCf, Hb, YS);
        zin_k<<<BT_*E_/4/256, 256, 0, stream>>>(YS, XC, XRES, D_param + (size_t)l*E_, XC /*in-place*/);
        gemm_k<0,0,128><<<dim3(BT_/BM, 2), 256, 0, stream>>>(
            XC, nullptr, E_, 0, WO + (size_t)l*E_*E_, E_, XIN /*y2*/, nullptr, nullptr, E_, E_);
        ln_k<<<BT_/4, 256, 0, stream>>>(XIN, xprev, ln_g + (size_t)l*E_, ln_b + (size_t)l*E_, xnext);
    }

    // ---- fusion: relu(concat([feats, ctx]) @ fus_w.T + fus_b) -> f32 d_out
    gemm_k<2,6,128><<<dim3(BT_/BM, 2), 256, 0, stream>>>(
        P1, CTXB, E_, 0, WF, 2*E_, d_out, nullptr, fus_b, E_, 2*E_);
    // ---- final layernorm, f32 in place on d_out ----
    ln_f32_k<<<BT_/4, 256, 0, stream>>>((const float*)d_out, fus_ln_g, fus_ln_b, (float*)d_out);

    // ---- probe: only writes if final output is all-zero (dead pipeline) ----
    probe_k<<<1, 64, 0, stream>>>((const unsigned int*)d_out, P0, P1, (float*)d_out);
}